// Round 8
// baseline (197.151 us; speedup 1.0000x reference)
//
#include <hip/hip_runtime.h>

#define HW 1659      // 21*79
#define PADID 4096
#define EMB 20
#define HID 32
#define MAXLEN 64

// ---------------- Kernel 1: 128-thread block-per-sample bag+emb (stable 46us) --
// R2 core, proj tail REMOVED (proj path deleted this round): grid = B exactly.
__global__ __launch_bounds__(128, 4) void bag_emb_kernel(
    const int* __restrict__ chars, const int* __restrict__ colors,
    const float* __restrict__ emb_table,
    float* __restrict__ out_emb, float* __restrict__ out_bag)
{
    const int tid = threadIdx.x;

    __shared__ __align__(16) unsigned char pres[4096];
    __shared__ int bagl[64];
    __shared__ int wsum[2];

    const int lane = tid & 63;
    const int wv   = tid >> 6;
    const int b    = blockIdx.x;

    const int base = b * HW;
    const int pe = (4 - (base & 3)) & 3;          // peel to 16B alignment
    const int nv = (HW - pe) >> 2;                // always 414 int4 groups
    const int nt = HW - pe - (nv << 2);           // tail 0..3
    const int4* c4 = (const int4*)(chars + base + pe);
    const int4* k4 = (const int4*)(colors + base + pe);

    // ---- hoist ALL loads up front (8 int4 = 32 VGPRs, independent) ----
    int4 ca0 = c4[tid],       ka0 = k4[tid];
    int4 ca1 = c4[tid + 128], ka1 = k4[tid + 128];
    int4 ca2 = c4[tid + 256], ka2 = k4[tid + 256];     // 383 < 414 always
    const bool has3 = (tid + 384) < nv;                // tid < 30
    const int i3 = has3 ? tid + 384 : tid;
    int4 ca3 = c4[i3], ka3 = k4[i3];
    int gp = -1, gt = -1;
    if (tid < pe) gp = (chars[base + tid] << 4) + colors[base + tid];
    if (tid < nt) {
        const int i = base + pe + (nv << 2) + tid;
        gt = (chars[i] << 4) + colors[i];
    }

    // zero presence map: 256 uint4 over 128 threads
    ((uint4*)pres)[tid]       = make_uint4(0u, 0u, 0u, 0u);
    ((uint4*)pres)[tid + 128] = make_uint4(0u, 0u, 0u, 0u);
    if (tid < 64) bagl[tid] = PADID;
    __syncthreads();

    pres[(ca0.x << 4) + ka0.x] = 1;
    pres[(ca0.y << 4) + ka0.y] = 1;
    pres[(ca0.z << 4) + ka0.z] = 1;
    pres[(ca0.w << 4) + ka0.w] = 1;
    pres[(ca1.x << 4) + ka1.x] = 1;
    pres[(ca1.y << 4) + ka1.y] = 1;
    pres[(ca1.z << 4) + ka1.z] = 1;
    pres[(ca1.w << 4) + ka1.w] = 1;
    pres[(ca2.x << 4) + ka2.x] = 1;
    pres[(ca2.y << 4) + ka2.y] = 1;
    pres[(ca2.z << 4) + ka2.z] = 1;
    pres[(ca2.w << 4) + ka2.w] = 1;
    if (has3) {
        pres[(ca3.x << 4) + ka3.x] = 1;
        pres[(ca3.y << 4) + ka3.y] = 1;
        pres[(ca3.z << 4) + ka3.z] = 1;
        pres[(ca3.w << 4) + ka3.w] = 1;
    }
    if (gp >= 0) pres[gp] = 1;
    if (gt >= 0) pres[gt] = 1;
    __syncthreads();

    // ---- round-based readback: round r covers ids [2048r, 2048r+2048) ----
    const unsigned M = 0x01010101u;
    int base_cnt = 0;
#pragma unroll 1
    for (int r = 0; r < 2; r++) {
        const uint4 w = ((const uint4*)pres)[tid + (r << 7)];
        const int cnt = __popc(w.x & M) + __popc(w.y & M)
                      + __popc(w.z & M) + __popc(w.w & M);
        int pre = cnt;
#pragma unroll
        for (int d = 1; d < 64; d <<= 1) {
            const int v = __shfl_up(pre, d, 64);
            if (lane >= d) pre += v;
        }
        if (lane == 63) wsum[wv] = pre;
        __syncthreads();
        const int w0 = wsum[0], w1 = wsum[1];
        int p = base_cnt + (wv ? w0 : 0) + pre - cnt;     // exclusive prefix
        if (p < 64) {
            const unsigned wrd[4] = {w.x, w.y, w.z, w.w};
            const int idbase = (r << 11) + (tid << 4);
#pragma unroll
            for (int c = 0; c < 4; c++) {
#pragma unroll
                for (int k = 0; k < 4; k++) {
                    if ((wrd[c] >> (8 * k)) & 1) {
                        if (p < 64) bagl[p] = idbase + 4 * c + k;
                        p++;
                    }
                }
            }
        }
        base_cnt += w0 + w1;                 // block-uniform running total
        if (base_cnt >= 64) break;           // bag full -> skip round 1
        __syncthreads();                     // rare path: protect wsum reuse
    }
    __syncthreads();                         // bagl ready

    if (tid < 64) out_bag[(size_t)b * 64 + tid] = (float)bagl[tid];

    // gather embedding rows: 320 float4 over 128 threads, coalesced writes
    const float4* tab4 = (const float4*)emb_table;
    float4* dst4 = (float4*)(out_emb + (size_t)b * (MAXLEN * EMB));
#pragma unroll
    for (int m = 0; m < 3; m++) {
        const int q = tid + (m << 7);
        if (q < MAXLEN * 5) {
            const int t = q / 5;
            const int mm = q - t * 5;
            const int row = bagl[t];
            dst4[q] = tab4[row * 5 + mm];
        }
    }
}

// ---------------- Kernel 2: RNN from out_emb (no proj, no gathers) -------------
// PROMOTED from fallback after R0-R7 ledger: every proj-path variant (6 designs:
// per-step gather / pinned / tight-loop / LDS-staged / chunked-vmcnt) sat at
// 60-110us; the common factor was the per-step random 8B gather from proj.
// This design has NO random gathers in the loop: per step it reads 80B of
// SEQUENTIAL out_emb (41MB total, freshly written -> L3-resident) + a 128B LDS
// broadcast of h. 4 samples per 128-thread block (32 lanes each), 2048 blocks,
// tiny LDS -> all resident. Issue math: ~50 wave-instr/step serving 2 samples
// -> aggregate ~11us; L3 re-read ~14us; predicted 15-40us wall.
__global__ __launch_bounds__(128, 4) void rnn_kernel_noproj(
    const float* __restrict__ emb, const float* __restrict__ bagf,
    const float* __restrict__ W_ih, const float* __restrict__ W_hh,
    const float* __restrict__ b_ih, const float* __restrict__ b_hh,
    float* __restrict__ out_h)
{
    __shared__ float hbuf[4][32];
    const int tid = threadIdx.x;
    const int ib  = tid >> 5;
    const int j   = tid & 31;
    const int b   = blockIdx.x * 4 + ib;

    float wih[EMB];
#pragma unroll
    for (int k = 0; k < EMB; k++) wih[k] = W_ih[j * EMB + k];
    float whh[HID];
#pragma unroll
    for (int k = 0; k < HID; k++) whh[k] = W_hh[j * HID + k];
    const float sbias = b_ih[j] + b_hh[j];

    const float* bp = bagf + (size_t)b * 64;
    unsigned long long m0 = __ballot(bp[j]      < 4095.5f);
    unsigned long long m1 = __ballot(bp[32 + j] < 4095.5f);
    const int half = ib & 1;
    const int len = __popc((unsigned)(m0 >> (half * 32)))
                  + __popc((unsigned)(m1 >> (half * 32)));

    hbuf[ib][j] = 0.f;
    asm volatile("s_waitcnt lgkmcnt(0)" ::: "memory");

    float h = 0.f;
    const float* xb = emb + (size_t)b * (MAXLEN * EMB);
    for (int t = 0; t < MAXLEN; t++) {
        const float4* xp = (const float4*)(xb + t * EMB);
        float4 x0 = xp[0], x1 = xp[1], x2 = xp[2], x3 = xp[3], x4 = xp[4];
        float s = sbias;
        const float4* hb4 = (const float4*)hbuf[ib];
#pragma unroll
        for (int m = 0; m < 8; m++) {
            float4 hv = hb4[m];
            s += whh[4*m+0]*hv.x + whh[4*m+1]*hv.y
               + whh[4*m+2]*hv.z + whh[4*m+3]*hv.w;
        }
        s += wih[0]*x0.x + wih[1]*x0.y + wih[2]*x0.z + wih[3]*x0.w;
        s += wih[4]*x1.x + wih[5]*x1.y + wih[6]*x1.z + wih[7]*x1.w;
        s += wih[8]*x2.x + wih[9]*x2.y + wih[10]*x2.z + wih[11]*x2.w;
        s += wih[12]*x3.x + wih[13]*x3.y + wih[14]*x3.z + wih[15]*x3.w;
        s += wih[16]*x4.x + wih[17]*x4.y + wih[18]*x4.z + wih[19]*x4.w;
        s = fminf(fmaxf(s, -9.f), 9.f);
        float e = __expf(2.f * s);
        float th = (e - 1.f) * __builtin_amdgcn_rcpf(e + 1.f);
        h = (t < len) ? th : h;
        hbuf[ib][j] = h;
        asm volatile("s_waitcnt lgkmcnt(0)" ::: "memory");
    }
    out_h[(size_t)b * HID + j] = h;
}

extern "C" void kernel_launch(void* const* d_in, const int* in_sizes, int n_in,
                              void* d_out, int out_size, void* d_ws, size_t ws_size,
                              hipStream_t stream) {
    const int*   chars     = (const int*)d_in[0];
    const int*   colors    = (const int*)d_in[1];
    const float* emb_table = (const float*)d_in[2];
    const float* W_ih      = (const float*)d_in[3];
    const float* W_hh      = (const float*)d_in[4];
    const float* b_ih      = (const float*)d_in[5];
    const float* b_hh      = (const float*)d_in[6];
    (void)d_ws; (void)ws_size;

    const int B = in_sizes[0] / HW;      // 8192

    float* out     = (float*)d_out;
    float* out_h   = out;                                    // [B, 32]
    float* out_emb = out + (size_t)B * HID;                  // [B, 64, 20]
    float* out_bag = out_emb + (size_t)B * MAXLEN * EMB;     // [B, 64]

    bag_emb_kernel<<<B, 128, 0, stream>>>(chars, colors, emb_table,
                                          out_emb, out_bag);
    rnn_kernel_noproj<<<(B + 3) / 4, 128, 0, stream>>>(out_emb, out_bag,
                                                       W_ih, W_hh,
                                                       b_ih, b_hh, out_h);
}